// Round 17
// baseline (805.370 us; speedup 1.0000x reference)
//
#include <hip/hip_runtime.h>

// ---------------- bf16 helpers ----------------

__device__ __forceinline__ unsigned short f2bf(float f) {
    unsigned u = __float_as_uint(f);
    unsigned r = (u + 0x7FFFu + ((u >> 16) & 1u)) >> 16;
    return (unsigned short)r;
}
__device__ __forceinline__ float bf2f(unsigned short u) {
    return __uint_as_float(((unsigned)u) << 16);
}

typedef __attribute__((ext_vector_type(8))) short bf16x8;
typedef __attribute__((ext_vector_type(4))) float f32x4;
typedef __attribute__((ext_vector_type(8))) unsigned short u16x8;

// ---------------- node GEMM via MFMA + attention scores ----------------
// Output H is SLICE-MAJOR bf16: Hs[slice][node][16], slice = 16 consecutive
// cols (matches the MFMA col-tile ct). Slice = 3.2MB -> fits one XCD L2.
template<int K, bool IN_BF16>
__global__ __launch_bounds__(256, 4)
void gat_gemm_mfma(const void* __restrict__ Xin, const float* __restrict__ W,
                   const float* __restrict__ a_s, const float* __restrict__ a_d,
                   unsigned short* __restrict__ Hs, float* __restrict__ sc_s,
                   float* __restrict__ sc_d, int nrows) {
    __shared__ unsigned short Xl[64 * K];
    __shared__ unsigned short Wt[K * 64];
    const int t = threadIdx.x;
    const int tile0 = blockIdx.x * 64;
    const int CPR = K / 8;

    for (int c = t; c < 64 * CPR; c += 256) {
        const int row = c / CPR;
        const int ch  = c % CPR;
        const int gr  = tile0 + row;
        u16x8 v;
        if (gr < nrows) {
            if (IN_BF16) {
                v = *reinterpret_cast<const u16x8*>((const unsigned short*)Xin + (size_t)gr * K + ch * 8);
            } else {
                const float* src = (const float*)Xin + (size_t)gr * K + ch * 8;
                const float4 f0 = *reinterpret_cast<const float4*>(src);
                const float4 f1 = *reinterpret_cast<const float4*>(src + 4);
                v[0] = f2bf(f0.x); v[1] = f2bf(f0.y); v[2] = f2bf(f0.z); v[3] = f2bf(f0.w);
                v[4] = f2bf(f1.x); v[5] = f2bf(f1.y); v[6] = f2bf(f1.z); v[7] = f2bf(f1.w);
            }
        } else {
#pragma unroll
            for (int i = 0; i < 8; i++) v[i] = 0;
        }
        *reinterpret_cast<u16x8*>(&Xl[row * K + ((ch * 8) ^ ((row & 7) << 3))]) = v;
    }
    for (int i = t; i < K * 64; i += 256) {
        const int k = i >> 6;
        const int n = i & 63;
        Wt[((k >> 3) * 64 + n) * 8 + (k & 7)] = f2bf(W[i]);
    }
    __syncthreads();

    const int lane = t & 63;
    const int wave = t >> 6;
    const int lg = lane >> 4;
    const int li = lane & 15;

    f32x4 acc[4] = {{0.f,0.f,0.f,0.f},{0.f,0.f,0.f,0.f},{0.f,0.f,0.f,0.f},{0.f,0.f,0.f,0.f}};
    const int r = wave * 16 + li;

#pragma unroll
    for (int s = 0; s < K / 32; s++) {
        const int acol = (s * 32 + lg * 8) ^ ((r & 7) << 3);
        const bf16x8 a = *reinterpret_cast<const bf16x8*>(&Xl[r * K + acol]);
#pragma unroll
        for (int ct = 0; ct < 4; ct++) {
            const bf16x8 b = *reinterpret_cast<const bf16x8*>(&Wt[((s * 4 + lg) * 64 + ct * 16 + li) * 8]);
            acc[ct] = __builtin_amdgcn_mfma_f32_16x16x32_bf16(a, b, acc[ct], 0, 0, 0);
        }
    }

    float asv[4], adv[4];
#pragma unroll
    for (int ct = 0; ct < 4; ct++) {
        asv[ct] = a_s[ct * 16 + li];
        adv[ct] = a_d[ct * 16 + li];
    }
#pragma unroll
    for (int reg = 0; reg < 4; reg++) {
        const int gr = tile0 + wave * 16 + lg * 4 + reg;
        float ps = 0.f, pd = 0.f;
        if (gr < nrows) {
#pragma unroll
            for (int ct = 0; ct < 4; ct++) {
                const float v = acc[ct][reg];
                Hs[((size_t)ct * nrows + gr) * 16 + li] = f2bf(v);   // slice-major
                ps += v * asv[ct];
                pd += v * adv[ct];
            }
        }
#pragma unroll
        for (int off = 8; off; off >>= 1) {
            ps += __shfl_xor(ps, off);
            pd += __shfl_xor(pd, off);
        }
        if (li == 0 && gr < nrows) {
            sc_s[gr] = ps;
            sc_d[gr] = pd;
        }
    }
}

// ---------------- CSR build: bucket hist -> bucket scan -> partition -> place
#define BSZ   512
#define NBITS 9
#define CH    4096

__global__ __launch_bounds__(256)
void bucket_hist_kernel(const int* __restrict__ dst, int* __restrict__ bhist, int E) {
    __shared__ int cnt[256];
    const int t = threadIdx.x;
    cnt[t] = 0;
    __syncthreads();
    const int tid = blockIdx.x * blockDim.x + t;
    const int stride = gridDim.x * blockDim.x;
    const int E4 = E >> 2;
    for (int i = tid; i < E4; i += stride) {
        const int4 d = reinterpret_cast<const int4*>(dst)[i];
        atomicAdd(&cnt[d.x >> NBITS], 1);
        atomicAdd(&cnt[d.y >> NBITS], 1);
        atomicAdd(&cnt[d.z >> NBITS], 1);
        atomicAdd(&cnt[d.w >> NBITS], 1);
    }
    for (int i = (E4 << 2) + tid; i < E; i += stride)
        atomicAdd(&cnt[dst[i] >> NBITS], 1);
    __syncthreads();
    if (cnt[t] > 0) atomicAdd(&bhist[t], cnt[t]);
}

__global__ void bucket_scan_kernel(const int* __restrict__ bhist, int* __restrict__ bbase,
                                   int* __restrict__ bcur, int NB, int E) {
    __shared__ int s[256];
    const int t = threadIdx.x;
    const int v = (t < NB) ? bhist[t] : 0;
    s[t] = v;
    __syncthreads();
    for (int off = 1; off < 256; off <<= 1) {
        int u = (t >= off) ? s[t - off] : 0;
        __syncthreads();
        s[t] += u;
        __syncthreads();
    }
    if (t < NB) {
        const int excl = s[t] - v;
        bbase[t] = excl;
        bcur[t] = excl;
    }
    if (t == 0) bbase[NB] = E;
}

__global__ __launch_bounds__(256)
void partition_kernel(const int* __restrict__ ei, int E,
                      int* __restrict__ bcur, unsigned* __restrict__ staged) {
    __shared__ int cnt[256], scantmp[256], excl[256], cnt2[256], gbase[256];
    __shared__ unsigned packed[CH];
    __shared__ unsigned char bid[CH];
    const int t = threadIdx.x;
    const int e0 = blockIdx.x * CH;

    cnt[t] = 0;
    cnt2[t] = 0;
    __syncthreads();

    unsigned pk[16];
    int bb[16];
#pragma unroll
    for (int i = 0; i < 16; i++) {
        const int e = e0 + i * 256 + t;
        if (e < E) {
            const int d = ei[E + e];
            const int s = ei[e];
            bb[i] = d >> NBITS;
            pk[i] = ((unsigned)(d & (BSZ - 1)) << 17) | (unsigned)s;
            atomicAdd(&cnt[bb[i]], 1);
        } else bb[i] = -1;
    }
    __syncthreads();

    int v = cnt[t];
    scantmp[t] = v;
    __syncthreads();
    for (int off = 1; off < 256; off <<= 1) {
        int u = (t >= off) ? scantmp[t - off] : 0;
        __syncthreads();
        scantmp[t] += u;
        __syncthreads();
    }
    excl[t] = scantmp[t] - v;
    if (v > 0) gbase[t] = atomicAdd(&bcur[t], v);
    __syncthreads();

#pragma unroll
    for (int i = 0; i < 16; i++) {
        if (bb[i] >= 0) {
            const int slot = atomicAdd(&cnt2[bb[i]], 1);
            const int p = excl[bb[i]] + slot;
            packed[p] = pk[i];
            bid[p] = (unsigned char)bb[i];
        }
    }
    __syncthreads();

    const int nvalid = min(CH, E - e0);
    for (int i = t; i < nvalid; i += 256) {
        const int b = bid[i];
        staged[gbase[b] + (i - excl[b])] = packed[i];
    }
}

__global__ __launch_bounds__(256)
void place_kernel(const unsigned* __restrict__ staged, const int* __restrict__ bbase,
                  int* __restrict__ rowptr, int* __restrict__ col, int N, int E, int NB) {
    __shared__ int nc[BSZ];
    __shared__ int rp[BSZ];
    __shared__ int pairs[256];
    const int b = blockIdx.x;
    const int n0 = b * BSZ;
    const int nn = min(BSZ, N - n0);
    const int t = threadIdx.x;

    nc[t] = 0;
    nc[t + 256] = 0;
    __syncthreads();

    const int lo = bbase[b];
    const int hi = bbase[b + 1];
    for (int e = lo + t; e < hi; e += 256)
        atomicAdd(&nc[staged[e] >> 17], 1);
    __syncthreads();

    const int c0 = nc[2 * t], c1 = nc[2 * t + 1];
    const int ps = c0 + c1;
    pairs[t] = ps;
    __syncthreads();
    for (int off = 1; off < 256; off <<= 1) {
        int u = (t >= off) ? pairs[t - off] : 0;
        __syncthreads();
        pairs[t] += u;
        __syncthreads();
    }
    const int pexcl = pairs[t] - ps;
    rp[2 * t]     = lo + pexcl;
    rp[2 * t + 1] = lo + pexcl + c0;
    nc[2 * t] = 0;
    nc[2 * t + 1] = 0;
    __syncthreads();

    for (int i = t; i < nn; i += 256) rowptr[n0 + i] = rp[i];
    if (b == NB - 1 && t == 0) rowptr[N] = E;

    for (int e = lo + t; e < hi; e += 256) {
        const unsigned p = staged[e];
        const int dlo = (int)(p >> 17);
        const int src = (int)(p & 0x1FFFFu);
        const int pos = rp[dlo] + atomicAdd(&nc[dlo], 1);
        col[pos] = src;
    }
}

// ---------------- pass A: per-node softmax (weights unnormalized) ------------
__global__ __launch_bounds__(256)
void agg_softmax_kernel(const int* __restrict__ rowptr, const int* __restrict__ col,
                        const float* __restrict__ sc_s, const float* __restrict__ sc_d,
                        float* __restrict__ pbuf, float* __restrict__ denomArr,
                        float* __restrict__ pselfArr, int N) {
    const int lane = threadIdx.x & 63;
    int gw = (blockIdx.x * blockDim.x + threadIdx.x) >> 6;
    const int nw = (gridDim.x * blockDim.x) >> 6;
    for (int i = gw; i < N; i += nw) {
        const float scd = sc_d[i];
        float es = sc_s[i] + scd;
        es = es > 0.f ? es : 0.2f * es;
        float m = es;
        const int jb = rowptr[i], je = rowptr[i + 1];
        for (int j = jb; j < je; j += 64) {
            const int nj = min(64, je - j);
            float el = -1e30f;
            if (lane < nj) {
                const int sl = col[j + lane];
                float ev = sc_s[sl] + scd;
                el = ev > 0.f ? ev : 0.2f * ev;
            }
#pragma unroll
            for (int off = 32; off; off >>= 1) el = fmaxf(el, __shfl_xor(el, off));
            m = fmaxf(m, el);
        }
        float dsum = 0.f;
        for (int j = jb; j < je; j += 64) {
            const int nj = min(64, je - j);
            float pl = 0.f;
            if (lane < nj) {
                const int sl = col[j + lane];
                float ev = sc_s[sl] + scd;
                ev = ev > 0.f ? ev : 0.2f * ev;
                pl = __expf(ev - m);
                pbuf[j + lane] = pl;
            }
#pragma unroll
            for (int off = 32; off; off >>= 1) pl += __shfl_xor(pl, off);
            dsum += pl;
        }
        const float pself = __expf(es - m);
        if (lane == 0) {
            denomArr[i] = pself + dsum;
            pselfArr[i] = pself;
        }
    }
}

// ---------------- pass B: sliced gather-accumulate ---------------------------
// slice = (blockIdx&7)>>1 (2 XCDs per slice). Self term added by group 0 ONLY
// (bugfix r16: all 4 groups added it -> 4x self weight).
template<bool RELU, bool OUTBF>
__global__ __launch_bounds__(256)
void agg_gather_kernel(const int* __restrict__ rowptr, const int* __restrict__ col,
                       const float* __restrict__ pbuf, const float* __restrict__ denomArr,
                       const float* __restrict__ pselfArr,
                       const unsigned short* __restrict__ Hs,
                       const float* __restrict__ bias, void* __restrict__ Out, int N) {
    const int t = threadIdx.x;
    const int lane = t & 63;
    const int g = lane >> 4;
    const int li = lane & 15;
    const int slice = (blockIdx.x & 7) >> 1;
    const int sb = (blockIdx.x >> 3) * 2 + (blockIdx.x & 1);
    const int swid = sb * 4 + (t >> 6);
    const int snw = (gridDim.x >> 3) * 2 * 4;
    const unsigned short* Hsl = Hs + (size_t)slice * N * 16;
    const float bl = bias[slice * 16 + li];

    for (int i = swid; i < N; i += snw) {
        const int jb = rowptr[i], je = rowptr[i + 1];
        float accA = (g == 0) ? pselfArr[i] * bf2f(Hsl[(size_t)i * 16 + li]) : 0.f;
        float accB = 0.f;
        int j0 = jb;
        for (; j0 + 8 <= je; j0 += 8) {
            const int ja = j0 + g;
            const int jc = j0 + 4 + g;
            const int sa = __builtin_nontemporal_load(col + ja);
            const int sc = __builtin_nontemporal_load(col + jc);
            const float pa = __builtin_nontemporal_load(pbuf + ja);
            const float pc = __builtin_nontemporal_load(pbuf + jc);
            accA += pa * bf2f(Hsl[(size_t)sa * 16 + li]);
            accB += pc * bf2f(Hsl[(size_t)sc * 16 + li]);
        }
        for (; j0 < je; j0 += 4) {
            const int ja = j0 + g;
            if (ja < je) {
                const int sa = __builtin_nontemporal_load(col + ja);
                const float pa = __builtin_nontemporal_load(pbuf + ja);
                accA += pa * bf2f(Hsl[(size_t)sa * 16 + li]);
            }
        }
        float acc = accA + accB;
        acc += __shfl_xor(acc, 16);
        acc += __shfl_xor(acc, 32);
        float o = acc / denomArr[i] + bl;
        if (RELU) o = o > 0.f ? o : 0.f;
        if (g == 0) {
            if (OUTBF) ((unsigned short*)Out)[(size_t)i * 64 + slice * 16 + li] = f2bf(o);
            else       ((float*)Out)[(size_t)i * 64 + slice * 16 + li] = o;
        }
    }
}

// ---------------- pooling (batch sorted; small chunks, many waves) ----------------

__global__ void pool_kernel(const float* __restrict__ H, const int* __restrict__ batch,
                            float* __restrict__ sums, int* __restrict__ cnts, int N) {
    const int CHUNK = 32;
    const int lane = threadIdx.x & 63;
    int gw = (blockIdx.x * blockDim.x + threadIdx.x) >> 6;
    const int nw = (gridDim.x * blockDim.x) >> 6;
    const int nchunks = (N + CHUNK - 1) / CHUNK;
    for (int c = gw; c < nchunks; c += nw) {
        const int lo = c * CHUNK;
        const int hi = min(lo + CHUNK, N);
        int curb = batch[lo];
        float acc = 0.f;
        int cnt = 0;
        for (int n = lo; n < hi; n++) {
            int b = batch[n];
            if (b != curb) {
                unsafeAtomicAdd(&sums[(size_t)curb * 64 + lane], acc);
                if (lane == 0) atomicAdd(&cnts[curb], cnt);
                acc = 0.f; cnt = 0; curb = b;
            }
            acc += H[(size_t)n * 64 + lane];
            cnt++;
        }
        unsafeAtomicAdd(&sums[(size_t)curb * 64 + lane], acc);
        if (lane == 0) atomicAdd(&cnts[curb], cnt);
    }
}

// ---------------- final MLP + log_softmax ----------------
__global__ void mlp_kernel(const float* __restrict__ sums, const int* __restrict__ cnts,
                           const float* __restrict__ lw, const float* __restrict__ lb,
                           const float* __restrict__ cw, const float* __restrict__ cb,
                           float* __restrict__ out) {
    __shared__ float gv[64];
    __shared__ float z[32];
    __shared__ float logits[6];
    const int g = blockIdx.x;
    const int t = threadIdx.x;

    float cnt = (float)cnts[g];
    cnt = cnt > 1.f ? cnt : 1.f;
    gv[t] = sums[(size_t)g * 64 + t] / cnt;
    __syncthreads();

    if (t < 32) {
        float acc = lb[t];
#pragma unroll
        for (int k = 0; k < 64; k++) acc += gv[k] * lw[k * 32 + t];
        z[t] = acc > 0.f ? acc : 0.f;
    }
    __syncthreads();
    if (t < 6) {
        float acc = cb[t];
#pragma unroll
        for (int k = 0; k < 32; k++) acc += z[k] * cw[k * 6 + t];
        logits[t] = acc;
    }
    __syncthreads();
    if (t == 0) {
        float m = logits[0];
#pragma unroll
        for (int i = 1; i < 6; i++) m = fmaxf(m, logits[i]);
        float s = 0.f;
#pragma unroll
        for (int i = 0; i < 6; i++) s += expf(logits[i] - m);
        float lse = m + logf(s);
#pragma unroll
        for (int i = 0; i < 6; i++) out[(size_t)g * 6 + i] = logits[i] - lse;
    }
}

// ---------------- launch ----------------

extern "C" void kernel_launch(void* const* d_in, const int* in_sizes, int n_in,
                              void* d_out, int out_size, void* d_ws, size_t ws_size,
                              hipStream_t stream) {
    const float* x    = (const float*)d_in[0];
    const int*   ei   = (const int*)d_in[1];
    const int*   batch= (const int*)d_in[2];
    const float* W1   = (const float*)d_in[3];
    const float* as1  = (const float*)d_in[4];
    const float* ad1  = (const float*)d_in[5];
    const float* b1   = (const float*)d_in[6];
    const float* W2   = (const float*)d_in[7];
    const float* as2  = (const float*)d_in[8];
    const float* ad2  = (const float*)d_in[9];
    const float* b2   = (const float*)d_in[10];
    const float* lw   = (const float*)d_in[11];
    const float* lb   = (const float*)d_in[12];
    const float* cw   = (const float*)d_in[13];
    const float* cb   = (const float*)d_in[14];
    float* out = (float*)d_out;

    const int N  = in_sizes[0] / 128;
    const int E  = in_sizes[1] / 2;
    const int G  = out_size / 6;
    const int NB = (N + BSZ - 1) / BSZ;

    char* ws = (char*)d_ws;
    size_t off = 0;
    auto alloc = [&](size_t bytes) {
        void* p = ws + off;
        off += (bytes + 255) & ~size_t(255);
        return p;
    };
    float*          hB     = (float*)alloc((size_t)N * 64 * 4);          // layer2 out (f32)
    unsigned short* hB1b   = (unsigned short*)alloc((size_t)N * 64 * 2); // layer1 out (bf16)
    unsigned short* Hs     = (unsigned short*)alloc((size_t)N * 64 * 2); // GEMM out slice-major
    float*          sc_s   = (float*)alloc((size_t)N * 4);
    float*          sc_d   = (float*)alloc((size_t)N * 4);
    float*          pbuf   = (float*)alloc((size_t)E * 4);
    float*          denA   = (float*)alloc((size_t)N * 4);
    float*          pself  = (float*)alloc((size_t)N * 4);
    int*            rowptr = (int*)alloc((size_t)(N + 1) * 4);
    int*            colidx = (int*)alloc((size_t)E * 4);
    unsigned*       staged = (unsigned*)alloc((size_t)E * 4);
    int*            bhist  = (int*)alloc((size_t)256 * 4);
    int*            bbase  = (int*)alloc((size_t)257 * 4);
    int*            bcur   = (int*)alloc((size_t)256 * 4);
    float*          psum   = (float*)alloc((size_t)G * 64 * 4);
    int*            pcnt   = (int*)alloc((size_t)G * 4);
    (void)ws_size;

    const int TB = 256;
    const int gemm_grid = (N + 63) / 64;
    const int part_blocks = (E + CH - 1) / CH;

    // ---- CSR build by dst ----
    hipMemsetAsync(bhist, 0, 256 * 4, stream);
    bucket_hist_kernel<<<1024, TB, 0, stream>>>(ei + E, bhist, E);
    bucket_scan_kernel<<<1, 256, 0, stream>>>(bhist, bbase, bcur, NB, E);
    partition_kernel<<<part_blocks, 256, 0, stream>>>(ei, E, bcur, staged);
    place_kernel<<<NB, 256, 0, stream>>>(staged, bbase, rowptr, colidx, N, E, NB);

    // ---- layer 1 ----
    gat_gemm_mfma<128, false><<<gemm_grid, TB, 0, stream>>>(x, W1, as1, ad1, Hs, sc_s, sc_d, N);
    agg_softmax_kernel<<<2048, TB, 0, stream>>>(rowptr, colidx, sc_s, sc_d, pbuf, denA, pself, N);
    agg_gather_kernel<true, true><<<2048, TB, 0, stream>>>(rowptr, colidx, pbuf, denA, pself,
                                                           Hs, b1, hB1b, N);

    // ---- layer 2 ----
    gat_gemm_mfma<64, true><<<gemm_grid, TB, 0, stream>>>(hB1b, W2, as2, ad2, Hs, sc_s, sc_d, N);
    agg_softmax_kernel<<<2048, TB, 0, stream>>>(rowptr, colidx, sc_s, sc_d, pbuf, denA, pself, N);
    agg_gather_kernel<false, false><<<2048, TB, 0, stream>>>(rowptr, colidx, pbuf, denA, pself,
                                                             Hs, b2, hB, N);

    // ---- pooling + MLP head ----
    hipMemsetAsync(psum, 0, (size_t)G * 64 * 4, stream);
    hipMemsetAsync(pcnt, 0, (size_t)G * 4, stream);
    pool_kernel<<<1024, TB, 0, stream>>>(hB, batch, psum, pcnt, N);
    mlp_kernel<<<G, 64, 0, stream>>>(psum, pcnt, lw, lb, cw, cb, out);
}

// Round 18
// 390.902 us; speedup vs baseline: 2.0603x; 2.0603x over previous
//
#include <hip/hip_runtime.h>

// ---------------- bf16 helpers ----------------

__device__ __forceinline__ unsigned short f2bf(float f) {
    unsigned u = __float_as_uint(f);
    unsigned r = (u + 0x7FFFu + ((u >> 16) & 1u)) >> 16;
    return (unsigned short)r;
}
__device__ __forceinline__ float bf2f(unsigned short u) {
    return __uint_as_float(((unsigned)u) << 16);
}

typedef __attribute__((ext_vector_type(8))) short bf16x8;
typedef __attribute__((ext_vector_type(4))) float f32x4;
typedef __attribute__((ext_vector_type(8))) unsigned short u16x8;

// ---------------- node GEMM via MFMA + attention scores (row-major Hb) -------
template<int K, bool IN_BF16>
__global__ __launch_bounds__(256, 4)
void gat_gemm_mfma(const void* __restrict__ Xin, const float* __restrict__ W,
                   const float* __restrict__ a_s, const float* __restrict__ a_d,
                   unsigned short* __restrict__ Hb, float* __restrict__ sc_s,
                   float* __restrict__ sc_d, int nrows) {
    __shared__ unsigned short Xl[64 * K];
    __shared__ unsigned short Wt[K * 64];
    const int t = threadIdx.x;
    const int tile0 = blockIdx.x * 64;
    const int CPR = K / 8;

    for (int c = t; c < 64 * CPR; c += 256) {
        const int row = c / CPR;
        const int ch  = c % CPR;
        const int gr  = tile0 + row;
        u16x8 v;
        if (gr < nrows) {
            if (IN_BF16) {
                v = *reinterpret_cast<const u16x8*>((const unsigned short*)Xin + (size_t)gr * K + ch * 8);
            } else {
                const float* src = (const float*)Xin + (size_t)gr * K + ch * 8;
                const float4 f0 = *reinterpret_cast<const float4*>(src);
                const float4 f1 = *reinterpret_cast<const float4*>(src + 4);
                v[0] = f2bf(f0.x); v[1] = f2bf(f0.y); v[2] = f2bf(f0.z); v[3] = f2bf(f0.w);
                v[4] = f2bf(f1.x); v[5] = f2bf(f1.y); v[6] = f2bf(f1.z); v[7] = f2bf(f1.w);
            }
        } else {
#pragma unroll
            for (int i = 0; i < 8; i++) v[i] = 0;
        }
        *reinterpret_cast<u16x8*>(&Xl[row * K + ((ch * 8) ^ ((row & 7) << 3))]) = v;
    }
    for (int i = t; i < K * 64; i += 256) {
        const int k = i >> 6;
        const int n = i & 63;
        Wt[((k >> 3) * 64 + n) * 8 + (k & 7)] = f2bf(W[i]);
    }
    __syncthreads();

    const int lane = t & 63;
    const int wave = t >> 6;
    const int lg = lane >> 4;
    const int li = lane & 15;

    f32x4 acc[4] = {{0.f,0.f,0.f,0.f},{0.f,0.f,0.f,0.f},{0.f,0.f,0.f,0.f},{0.f,0.f,0.f,0.f}};
    const int r = wave * 16 + li;

#pragma unroll
    for (int s = 0; s < K / 32; s++) {
        const int acol = (s * 32 + lg * 8) ^ ((r & 7) << 3);
        const bf16x8 a = *reinterpret_cast<const bf16x8*>(&Xl[r * K + acol]);
#pragma unroll
        for (int ct = 0; ct < 4; ct++) {
            const bf16x8 b = *reinterpret_cast<const bf16x8*>(&Wt[((s * 4 + lg) * 64 + ct * 16 + li) * 8]);
            acc[ct] = __builtin_amdgcn_mfma_f32_16x16x32_bf16(a, b, acc[ct], 0, 0, 0);
        }
    }

    float asv[4], adv[4];
#pragma unroll
    for (int ct = 0; ct < 4; ct++) {
        asv[ct] = a_s[ct * 16 + li];
        adv[ct] = a_d[ct * 16 + li];
    }
#pragma unroll
    for (int reg = 0; reg < 4; reg++) {
        const int gr = tile0 + wave * 16 + lg * 4 + reg;
        float ps = 0.f, pd = 0.f;
        if (gr < nrows) {
#pragma unroll
            for (int ct = 0; ct < 4; ct++) {
                const float v = acc[ct][reg];
                Hb[(size_t)gr * 64 + ct * 16 + li] = f2bf(v);
                ps += v * asv[ct];
                pd += v * adv[ct];
            }
        }
#pragma unroll
        for (int off = 8; off; off >>= 1) {
            ps += __shfl_xor(ps, off);
            pd += __shfl_xor(pd, off);
        }
        if (li == 0 && gr < nrows) {
            sc_s[gr] = ps;
            sc_d[gr] = pd;
        }
    }
}

// ---------------- CSR build: bucket hist -> bucket scan -> partition -> place
#define BSZ   512
#define NBITS 9
#define CH    4096

__global__ __launch_bounds__(256)
void bucket_hist_kernel(const int* __restrict__ dst, int* __restrict__ bhist, int E) {
    __shared__ int cnt[256];
    const int t = threadIdx.x;
    cnt[t] = 0;
    __syncthreads();
    const int tid = blockIdx.x * blockDim.x + t;
    const int stride = gridDim.x * blockDim.x;
    const int E4 = E >> 2;
    for (int i = tid; i < E4; i += stride) {
        const int4 d = reinterpret_cast<const int4*>(dst)[i];
        atomicAdd(&cnt[d.x >> NBITS], 1);
        atomicAdd(&cnt[d.y >> NBITS], 1);
        atomicAdd(&cnt[d.z >> NBITS], 1);
        atomicAdd(&cnt[d.w >> NBITS], 1);
    }
    for (int i = (E4 << 2) + tid; i < E; i += stride)
        atomicAdd(&cnt[dst[i] >> NBITS], 1);
    __syncthreads();
    if (cnt[t] > 0) atomicAdd(&bhist[t], cnt[t]);
}

__global__ void bucket_scan_kernel(const int* __restrict__ bhist, int* __restrict__ bbase,
                                   int* __restrict__ bcur, int NB, int E) {
    __shared__ int s[256];
    const int t = threadIdx.x;
    const int v = (t < NB) ? bhist[t] : 0;
    s[t] = v;
    __syncthreads();
    for (int off = 1; off < 256; off <<= 1) {
        int u = (t >= off) ? s[t - off] : 0;
        __syncthreads();
        s[t] += u;
        __syncthreads();
    }
    if (t < NB) {
        const int excl = s[t] - v;
        bbase[t] = excl;
        bcur[t] = excl;
    }
    if (t == 0) bbase[NB] = E;
}

__global__ __launch_bounds__(256)
void partition_kernel(const int* __restrict__ ei, int E,
                      int* __restrict__ bcur, unsigned* __restrict__ staged) {
    __shared__ int cnt[256], scantmp[256], excl[256], cnt2[256], gbase[256];
    __shared__ unsigned packed[CH];
    __shared__ unsigned char bid[CH];
    const int t = threadIdx.x;
    const int e0 = blockIdx.x * CH;

    cnt[t] = 0;
    cnt2[t] = 0;
    __syncthreads();

    unsigned pk[16];
    int bb[16];
#pragma unroll
    for (int i = 0; i < 16; i++) {
        const int e = e0 + i * 256 + t;
        if (e < E) {
            const int d = ei[E + e];
            const int s = ei[e];
            bb[i] = d >> NBITS;
            pk[i] = ((unsigned)(d & (BSZ - 1)) << 17) | (unsigned)s;
            atomicAdd(&cnt[bb[i]], 1);
        } else bb[i] = -1;
    }
    __syncthreads();

    int v = cnt[t];
    scantmp[t] = v;
    __syncthreads();
    for (int off = 1; off < 256; off <<= 1) {
        int u = (t >= off) ? scantmp[t - off] : 0;
        __syncthreads();
        scantmp[t] += u;
        __syncthreads();
    }
    excl[t] = scantmp[t] - v;
    if (v > 0) gbase[t] = atomicAdd(&bcur[t], v);
    __syncthreads();

#pragma unroll
    for (int i = 0; i < 16; i++) {
        if (bb[i] >= 0) {
            const int slot = atomicAdd(&cnt2[bb[i]], 1);
            const int p = excl[bb[i]] + slot;
            packed[p] = pk[i];
            bid[p] = (unsigned char)bb[i];
        }
    }
    __syncthreads();

    const int nvalid = min(CH, E - e0);
    for (int i = t; i < nvalid; i += 256) {
        const int b = bid[i];
        staged[gbase[b] + (i - excl[b])] = packed[i];
    }
}

__global__ __launch_bounds__(256)
void place_kernel(const unsigned* __restrict__ staged, const int* __restrict__ bbase,
                  int* __restrict__ rowptr, int* __restrict__ col, int N, int E, int NB) {
    __shared__ int nc[BSZ];
    __shared__ int rp[BSZ];
    __shared__ int pairs[256];
    const int b = blockIdx.x;
    const int n0 = b * BSZ;
    const int nn = min(BSZ, N - n0);
    const int t = threadIdx.x;

    nc[t] = 0;
    nc[t + 256] = 0;
    __syncthreads();

    const int lo = bbase[b];
    const int hi = bbase[b + 1];
    for (int e = lo + t; e < hi; e += 256)
        atomicAdd(&nc[staged[e] >> 17], 1);
    __syncthreads();

    const int c0 = nc[2 * t], c1 = nc[2 * t + 1];
    const int ps = c0 + c1;
    pairs[t] = ps;
    __syncthreads();
    for (int off = 1; off < 256; off <<= 1) {
        int u = (t >= off) ? pairs[t - off] : 0;
        __syncthreads();
        pairs[t] += u;
        __syncthreads();
    }
    const int pexcl = pairs[t] - ps;
    rp[2 * t]     = lo + pexcl;
    rp[2 * t + 1] = lo + pexcl + c0;
    nc[2 * t] = 0;
    nc[2 * t + 1] = 0;
    __syncthreads();

    for (int i = t; i < nn; i += 256) rowptr[n0 + i] = rp[i];
    if (b == NB - 1 && t == 0) rowptr[N] = E;

    for (int e = lo + t; e < hi; e += 256) {
        const unsigned p = staged[e];
        const int dlo = (int)(p >> 17);
        const int src = (int)(p & 0x1FFFFu);
        const int pos = rp[dlo] + atomicAdd(&nc[dlo], 1);
        col[pos] = src;
    }
}

// ---------------- fused per-node online-softmax aggregation ------------------
// 32-lanes-per-node pairing: wave half h owns node 2p+h; each lane covers 2
// columns (ushort2). One gather instruction serves TWO rows (one per half) ->
// half the instructions per edge at identical bytes. Softmax reduces use
// __shfl_xor offsets <=16 (intra-half). Phase-2 broadcasts via __shfl width=32.
template<bool RELU, bool OUTBF>
__global__ void gat_fused_agg(const int* __restrict__ rowptr, const int* __restrict__ col,
                              const float* __restrict__ sc_s, const float* __restrict__ sc_d,
                              const unsigned short* __restrict__ Hb, const float* __restrict__ bias,
                              void* __restrict__ Out, int N) {
    const int lane = threadIdx.x & 63;
    const int hl = lane & 31;          // lane within half
    int gw = (blockIdx.x * blockDim.x + threadIdx.x) >> 6;
    const int nw = (gridDim.x * blockDim.x) >> 6;
    const float bl0 = bias[2 * hl];
    const float bl1 = bias[2 * hl + 1];
    const char* hb2 = (const char*)Hb + 4 * hl;   // lane's 4B (2 cols) within a row
    const int npairs = (N + 1) >> 1;

    for (int p = gw; p < npairs; p += nw) {
        const int i = 2 * p + (lane >> 5);       // node for this half
        const bool valid = (i < N);
        float scd = 0.f, m = 0.f, denom = 1.f;
        float acc0 = 0.f, acc1 = 0.f;
        int j = 0, je = 0;
        if (valid) {
            scd = sc_d[i];
            float es = sc_s[i] + scd;
            es = es > 0.f ? es : 0.2f * es;
            m = es;                               // self seeds: weight 1
            const ushort2 hs = *(const ushort2*)(hb2 + ((size_t)i << 7));
            acc0 = bf2f(hs.x);
            acc1 = bf2f(hs.y);
            j = rowptr[i];
            je = rowptr[i + 1];
        }

        while (__any(j < je)) {
            const int nj = (j < je) ? min(32, je - j) : 0;   // uniform per half
            int soff = 0;
            float el = -1e30f;
            if (hl < nj) {
                const int sl = col[j + hl];
                soff = sl << 7;
                const float ev = sc_s[sl] + scd;
                el = ev > 0.f ? ev : 0.2f * ev;
            }
            // intra-half max reduce
            float cm = el;
#pragma unroll
            for (int off = 16; off; off >>= 1) cm = fmaxf(cm, __shfl_xor(cm, off));
            float wl = 0.f;
            if (nj > 0) {
                const float mn = fmaxf(m, cm);
                wl = (hl < nj) ? __expf(el - mn) : 0.f;
                float wsum = wl;
#pragma unroll
                for (int off = 16; off; off >>= 1) wsum += __shfl_xor(wsum, off);
                const float scale = __expf(m - mn);
                denom = denom * scale + wsum;
                acc0 *= scale;
                acc1 *= scale;
                m = mn;
            }
            // phase 2: broadcast within half; one load instr = 2 rows (both halves)
            const int wb = __float_as_int(wl);
            int njo = nj;
            const int njmax = max(nj, __shfl_xor(nj, 32));
            for (int q = 0; q < njmax; q += 4) {
                const int o0 = __shfl(soff, q, 32);
                const int o1 = __shfl(soff, q + 1, 32);
                const int o2 = __shfl(soff, q + 2, 32);
                const int o3 = __shfl(soff, q + 3, 32);
                const float w0 = __int_as_float(__shfl(wb, q, 32));
                const float w1 = __int_as_float(__shfl(wb, q + 1, 32));
                const float w2 = __int_as_float(__shfl(wb, q + 2, 32));
                const float w3 = __int_as_float(__shfl(wb, q + 3, 32));
                if (q < njo) {
                    const ushort2 h = *(const ushort2*)(hb2 + o0);
                    acc0 += w0 * bf2f(h.x);
                    acc1 += w0 * bf2f(h.y);
                }
                if (q + 1 < njo) {
                    const ushort2 h = *(const ushort2*)(hb2 + o1);
                    acc0 += w1 * bf2f(h.x);
                    acc1 += w1 * bf2f(h.y);
                }
                if (q + 2 < njo) {
                    const ushort2 h = *(const ushort2*)(hb2 + o2);
                    acc0 += w2 * bf2f(h.x);
                    acc1 += w2 * bf2f(h.y);
                }
                if (q + 3 < njo) {
                    const ushort2 h = *(const ushort2*)(hb2 + o3);
                    acc0 += w3 * bf2f(h.x);
                    acc1 += w3 * bf2f(h.y);
                }
            }
            j += 32;
        }

        if (valid) {
            float o0 = acc0 / denom + bl0;
            float o1 = acc1 / denom + bl1;
            if (RELU) {
                o0 = o0 > 0.f ? o0 : 0.f;
                o1 = o1 > 0.f ? o1 : 0.f;
            }
            if (OUTBF) {
                ushort2 h;
                h.x = f2bf(o0);
                h.y = f2bf(o1);
                *(ushort2*)((unsigned short*)Out + (size_t)i * 64 + 2 * hl) = h;
            } else {
                float2 f;
                f.x = o0;
                f.y = o1;
                *(float2*)((float*)Out + (size_t)i * 64 + 2 * hl) = f;
            }
        }
    }
}

// ---------------- pooling (batch sorted; small chunks, many waves) ----------------

__global__ void pool_kernel(const float* __restrict__ H, const int* __restrict__ batch,
                            float* __restrict__ sums, int* __restrict__ cnts, int N) {
    const int CHUNK = 32;
    const int lane = threadIdx.x & 63;
    int gw = (blockIdx.x * blockDim.x + threadIdx.x) >> 6;
    const int nw = (gridDim.x * blockDim.x) >> 6;
    const int nchunks = (N + CHUNK - 1) / CHUNK;
    for (int c = gw; c < nchunks; c += nw) {
        const int lo = c * CHUNK;
        const int hi = min(lo + CHUNK, N);
        int curb = batch[lo];
        float acc = 0.f;
        int cnt = 0;
        for (int n = lo; n < hi; n++) {
            int b = batch[n];
            if (b != curb) {
                unsafeAtomicAdd(&sums[(size_t)curb * 64 + lane], acc);
                if (lane == 0) atomicAdd(&cnts[curb], cnt);
                acc = 0.f; cnt = 0; curb = b;
            }
            acc += H[(size_t)n * 64 + lane];
            cnt++;
        }
        unsafeAtomicAdd(&sums[(size_t)curb * 64 + lane], acc);
        if (lane == 0) atomicAdd(&cnts[curb], cnt);
    }
}

// ---------------- final MLP + log_softmax ----------------
__global__ void mlp_kernel(const float* __restrict__ sums, const int* __restrict__ cnts,
                           const float* __restrict__ lw, const float* __restrict__ lb,
                           const float* __restrict__ cw, const float* __restrict__ cb,
                           float* __restrict__ out) {
    __shared__ float gv[64];
    __shared__ float z[32];
    __shared__ float logits[6];
    const int g = blockIdx.x;
    const int t = threadIdx.x;

    float cnt = (float)cnts[g];
    cnt = cnt > 1.f ? cnt : 1.f;
    gv[t] = sums[(size_t)g * 64 + t] / cnt;
    __syncthreads();

    if (t < 32) {
        float acc = lb[t];
#pragma unroll
        for (int k = 0; k < 64; k++) acc += gv[k] * lw[k * 32 + t];
        z[t] = acc > 0.f ? acc : 0.f;
    }
    __syncthreads();
    if (t < 6) {
        float acc = cb[t];
#pragma unroll
        for (int k = 0; k < 32; k++) acc += z[k] * cw[k * 6 + t];
        logits[t] = acc;
    }
    __syncthreads();
    if (t == 0) {
        float m = logits[0];
#pragma unroll
        for (int i = 1; i < 6; i++) m = fmaxf(m, logits[i]);
        float s = 0.f;
#pragma unroll
        for (int i = 0; i < 6; i++) s += expf(logits[i] - m);
        float lse = m + logf(s);
#pragma unroll
        for (int i = 0; i < 6; i++) out[(size_t)g * 6 + i] = logits[i] - lse;
    }
}

// ---------------- launch ----------------

extern "C" void kernel_launch(void* const* d_in, const int* in_sizes, int n_in,
                              void* d_out, int out_size, void* d_ws, size_t ws_size,
                              hipStream_t stream) {
    const float* x    = (const float*)d_in[0];
    const int*   ei   = (const int*)d_in[1];
    const int*   batch= (const int*)d_in[2];
    const float* W1   = (const float*)d_in[3];
    const float* as1  = (const float*)d_in[4];
    const float* ad1  = (const float*)d_in[5];
    const float* b1   = (const float*)d_in[6];
    const float* W2   = (const float*)d_in[7];
    const float* as2  = (const float*)d_in[8];
    const float* ad2  = (const float*)d_in[9];
    const float* b2   = (const float*)d_in[10];
    const float* lw   = (const float*)d_in[11];
    const float* lb   = (const float*)d_in[12];
    const float* cw   = (const float*)d_in[13];
    const float* cb   = (const float*)d_in[14];
    float* out = (float*)d_out;

    const int N  = in_sizes[0] / 128;
    const int E  = in_sizes[1] / 2;
    const int G  = out_size / 6;
    const int NB = (N + BSZ - 1) / BSZ;

    char* ws = (char*)d_ws;
    size_t off = 0;
    auto alloc = [&](size_t bytes) {
        void* p = ws + off;
        off += (bytes + 255) & ~size_t(255);
        return p;
    };
    float*          hB     = (float*)alloc((size_t)N * 64 * 4);
    unsigned short* hB1b   = (unsigned short*)alloc((size_t)N * 64 * 2);
    unsigned short* Hb     = (unsigned short*)alloc((size_t)N * 64 * 2);
    float*          sc_s   = (float*)alloc((size_t)N * 4);
    float*          sc_d   = (float*)alloc((size_t)N * 4);
    int*            rowptr = (int*)alloc((size_t)(N + 1) * 4);
    int*            colidx = (int*)alloc((size_t)E * 4);
    unsigned*       staged = (unsigned*)alloc((size_t)E * 4);
    int*            bhist  = (int*)alloc((size_t)256 * 4);
    int*            bbase  = (int*)alloc((size_t)257 * 4);
    int*            bcur   = (int*)alloc((size_t)256 * 4);
    float*          psum   = (float*)alloc((size_t)G * 64 * 4);
    int*            pcnt   = (int*)alloc((size_t)G * 4);
    (void)ws_size;

    const int TB = 256;
    const int gemm_grid = (N + 63) / 64;
    const int part_blocks = (E + CH - 1) / CH;

    // ---- CSR build by dst ----
    hipMemsetAsync(bhist, 0, 256 * 4, stream);
    bucket_hist_kernel<<<1024, TB, 0, stream>>>(ei + E, bhist, E);
    bucket_scan_kernel<<<1, 256, 0, stream>>>(bhist, bbase, bcur, NB, E);
    partition_kernel<<<part_blocks, 256, 0, stream>>>(ei, E, bcur, staged);
    place_kernel<<<NB, 256, 0, stream>>>(staged, bbase, rowptr, colidx, N, E, NB);

    // ---- layer 1 ----
    gat_gemm_mfma<128, false><<<gemm_grid, TB, 0, stream>>>(x, W1, as1, ad1, Hb, sc_s, sc_d, N);
    gat_fused_agg<true, true><<<2048, TB, 0, stream>>>(rowptr, colidx, sc_s, sc_d, Hb, b1, hB1b, N);

    // ---- layer 2 ----
    gat_gemm_mfma<64, true><<<gemm_grid, TB, 0, stream>>>(hB1b, W2, as2, ad2, Hb, sc_s, sc_d, N);
    gat_fused_agg<false, false><<<2048, TB, 0, stream>>>(rowptr, colidx, sc_s, sc_d, Hb, b2, hB, N);

    // ---- pooling + MLP head ----
    hipMemsetAsync(psum, 0, (size_t)G * 64 * 4, stream);
    hipMemsetAsync(pcnt, 0, (size_t)G * 4, stream);
    pool_kernel<<<1024, TB, 0, stream>>>(hB, batch, psum, pcnt, N);
    mlp_kernel<<<G, 64, 0, stream>>>(psum, pcnt, lw, lb, cw, cb, out);
}

// Round 19
// 301.049 us; speedup vs baseline: 2.6752x; 1.2985x over previous
//
#include <hip/hip_runtime.h>

// ---------------- bf16 helpers ----------------

__device__ __forceinline__ unsigned short f2bf(float f) {
    unsigned u = __float_as_uint(f);
    unsigned r = (u + 0x7FFFu + ((u >> 16) & 1u)) >> 16;
    return (unsigned short)r;
}
__device__ __forceinline__ float bf2f(unsigned short u) {
    return __uint_as_float(((unsigned)u) << 16);
}

typedef __attribute__((ext_vector_type(8))) short bf16x8;
typedef __attribute__((ext_vector_type(4))) float f32x4;
typedef __attribute__((ext_vector_type(8))) unsigned short u16x8;

// ---------------- node GEMM via MFMA + attention scores ----------------
template<int K, bool IN_BF16>
__global__ __launch_bounds__(256, 4)
void gat_gemm_mfma(const void* __restrict__ Xin, const float* __restrict__ W,
                   const float* __restrict__ a_s, const float* __restrict__ a_d,
                   unsigned short* __restrict__ Hb, float* __restrict__ sc_s,
                   float* __restrict__ sc_d, int nrows) {
    __shared__ unsigned short Xl[64 * K];
    __shared__ unsigned short Wt[K * 64];
    const int t = threadIdx.x;
    const int tile0 = blockIdx.x * 64;
    const int CPR = K / 8;

    for (int c = t; c < 64 * CPR; c += 256) {
        const int row = c / CPR;
        const int ch  = c % CPR;
        const int gr  = tile0 + row;
        u16x8 v;
        if (gr < nrows) {
            if (IN_BF16) {
                v = *reinterpret_cast<const u16x8*>((const unsigned short*)Xin + (size_t)gr * K + ch * 8);
            } else {
                const float* src = (const float*)Xin + (size_t)gr * K + ch * 8;
                const float4 f0 = *reinterpret_cast<const float4*>(src);
                const float4 f1 = *reinterpret_cast<const float4*>(src + 4);
                v[0] = f2bf(f0.x); v[1] = f2bf(f0.y); v[2] = f2bf(f0.z); v[3] = f2bf(f0.w);
                v[4] = f2bf(f1.x); v[5] = f2bf(f1.y); v[6] = f2bf(f1.z); v[7] = f2bf(f1.w);
            }
        } else {
#pragma unroll
            for (int i = 0; i < 8; i++) v[i] = 0;
        }
        *reinterpret_cast<u16x8*>(&Xl[row * K + ((ch * 8) ^ ((row & 7) << 3))]) = v;
    }
    for (int i = t; i < K * 64; i += 256) {
        const int k = i >> 6;
        const int n = i & 63;
        Wt[((k >> 3) * 64 + n) * 8 + (k & 7)] = f2bf(W[i]);
    }
    __syncthreads();

    const int lane = t & 63;
    const int wave = t >> 6;
    const int lg = lane >> 4;
    const int li = lane & 15;

    f32x4 acc[4] = {{0.f,0.f,0.f,0.f},{0.f,0.f,0.f,0.f},{0.f,0.f,0.f,0.f},{0.f,0.f,0.f,0.f}};
    const int r = wave * 16 + li;

#pragma unroll
    for (int s = 0; s < K / 32; s++) {
        const int acol = (s * 32 + lg * 8) ^ ((r & 7) << 3);
        const bf16x8 a = *reinterpret_cast<const bf16x8*>(&Xl[r * K + acol]);
#pragma unroll
        for (int ct = 0; ct < 4; ct++) {
            const bf16x8 b = *reinterpret_cast<const bf16x8*>(&Wt[((s * 4 + lg) * 64 + ct * 16 + li) * 8]);
            acc[ct] = __builtin_amdgcn_mfma_f32_16x16x32_bf16(a, b, acc[ct], 0, 0, 0);
        }
    }

    float asv[4], adv[4];
#pragma unroll
    for (int ct = 0; ct < 4; ct++) {
        asv[ct] = a_s[ct * 16 + li];
        adv[ct] = a_d[ct * 16 + li];
    }
#pragma unroll
    for (int reg = 0; reg < 4; reg++) {
        const int gr = tile0 + wave * 16 + lg * 4 + reg;
        float ps = 0.f, pd = 0.f;
        if (gr < nrows) {
#pragma unroll
            for (int ct = 0; ct < 4; ct++) {
                const float v = acc[ct][reg];
                Hb[(size_t)gr * 64 + ct * 16 + li] = f2bf(v);
                ps += v * asv[ct];
                pd += v * adv[ct];
            }
        }
#pragma unroll
        for (int off = 8; off; off >>= 1) {
            ps += __shfl_xor(ps, off);
            pd += __shfl_xor(pd, off);
        }
        if (li == 0 && gr < nrows) {
            sc_s[gr] = ps;
            sc_d[gr] = pd;
        }
    }
}

// ---------------- CSR build: partition (slack buckets) -> scan -> place ------
// No pre-histogram: each bucket owns a fixed CAP-slot run of staged[];
// partition reserves via bcur[b] (init b*CAP); post-scan of realized counts
// gives the exact col-array bucket bases.
#define BSZ   512
#define NBITS 9
#define CH    4096
#define BCAP  20480   // >= 60 sigma above E/NB for uniform random dst

__global__ void bucket_init_kernel(int* __restrict__ bcur, int NB) {
    const int t = threadIdx.x;
    if (t < NB) bcur[t] = t * BCAP;
}

__global__ __launch_bounds__(256)
void partition_kernel(const int* __restrict__ ei, int E,
                      int* __restrict__ bcur, unsigned* __restrict__ staged) {
    __shared__ int cnt[256], scantmp[256], excl[256], cnt2[256], gbase[256];
    __shared__ unsigned packed[CH];
    __shared__ unsigned char bid[CH];
    const int t = threadIdx.x;
    const int e0 = blockIdx.x * CH;

    cnt[t] = 0;
    cnt2[t] = 0;
    __syncthreads();

    unsigned pk[16];
    int bb[16];
#pragma unroll
    for (int i = 0; i < 16; i++) {
        const int e = e0 + i * 256 + t;
        if (e < E) {
            const int d = ei[E + e];
            const int s = ei[e];
            bb[i] = d >> NBITS;
            pk[i] = ((unsigned)(d & (BSZ - 1)) << 17) | (unsigned)s;
            atomicAdd(&cnt[bb[i]], 1);
        } else bb[i] = -1;
    }
    __syncthreads();

    int v = cnt[t];
    scantmp[t] = v;
    __syncthreads();
    for (int off = 1; off < 256; off <<= 1) {
        int u = (t >= off) ? scantmp[t - off] : 0;
        __syncthreads();
        scantmp[t] += u;
        __syncthreads();
    }
    excl[t] = scantmp[t] - v;
    if (v > 0) gbase[t] = atomicAdd(&bcur[t], v);
    __syncthreads();

#pragma unroll
    for (int i = 0; i < 16; i++) {
        if (bb[i] >= 0) {
            const int slot = atomicAdd(&cnt2[bb[i]], 1);
            const int p = excl[bb[i]] + slot;
            packed[p] = pk[i];
            bid[p] = (unsigned char)bb[i];
        }
    }
    __syncthreads();

    const int nvalid = min(CH, E - e0);
    for (int i = t; i < nvalid; i += 256) {
        const int b = bid[i];
        staged[gbase[b] + (i - excl[b])] = packed[i];
    }
}

// exclusive scan of realized bucket counts -> bbase (col-array bucket bases)
__global__ void bucket_scan_kernel(const int* __restrict__ bcur, int* __restrict__ bbase,
                                   int NB, int E) {
    __shared__ int s[256];
    const int t = threadIdx.x;
    const int v = (t < NB) ? (bcur[t] - t * BCAP) : 0;
    s[t] = v;
    __syncthreads();
    for (int off = 1; off < 256; off <<= 1) {
        int u = (t >= off) ? s[t - off] : 0;
        __syncthreads();
        s[t] += u;
        __syncthreads();
    }
    if (t < NB) bbase[t] = s[t] - v;
    if (t == 0) bbase[NB] = E;
}

// Phase D: one block per bucket; staged run at [b*BCAP, bcur[b]); col base bbase[b].
__global__ __launch_bounds__(256)
void place_kernel(const unsigned* __restrict__ staged, const int* __restrict__ bcur,
                  const int* __restrict__ bbase, int* __restrict__ rowptr,
                  int* __restrict__ col, int N, int E, int NB) {
    __shared__ int nc[BSZ];
    __shared__ int rp[BSZ];
    __shared__ int pairs[256];
    const int b = blockIdx.x;
    const int n0 = b * BSZ;
    const int nn = min(BSZ, N - n0);
    const int t = threadIdx.x;

    nc[t] = 0;
    nc[t + 256] = 0;
    __syncthreads();

    const int slo = b * BCAP;
    const int shi = bcur[b];
    const int colbase = bbase[b];
    for (int e = slo + t; e < shi; e += 256)
        atomicAdd(&nc[staged[e] >> 17], 1);
    __syncthreads();

    const int c0 = nc[2 * t], c1 = nc[2 * t + 1];
    const int ps = c0 + c1;
    pairs[t] = ps;
    __syncthreads();
    for (int off = 1; off < 256; off <<= 1) {
        int u = (t >= off) ? pairs[t - off] : 0;
        __syncthreads();
        pairs[t] += u;
        __syncthreads();
    }
    const int pexcl = pairs[t] - ps;
    rp[2 * t]     = colbase + pexcl;
    rp[2 * t + 1] = colbase + pexcl + c0;
    nc[2 * t] = 0;
    nc[2 * t + 1] = 0;
    __syncthreads();

    for (int i = t; i < nn; i += 256) rowptr[n0 + i] = rp[i];
    if (b == NB - 1 && t == 0) rowptr[N] = E;

    for (int e = slo + t; e < shi; e += 256) {
        const unsigned p = staged[e];
        const int dlo = (int)(p >> 17);
        const int src = (int)(p & 0x1FFFFu);
        const int pos = rp[dlo] + atomicAdd(&nc[dlo], 1);
        col[pos] = src;
    }
}

// ---------------- fused per-node online-softmax aggregation ------------------
// (r14 form — best measured: 64 lanes/node, TWO nodes per wave with staggered
// phase-1 gathers; sequential 4-deep broadcast phase-2.)
template<bool RELU, bool OUTBF>
__global__ void gat_fused_agg(const int* __restrict__ rowptr, const int* __restrict__ col,
                              const float* __restrict__ sc_s, const float* __restrict__ sc_d,
                              const unsigned short* __restrict__ Hb, const float* __restrict__ bias,
                              void* __restrict__ Out, int N) {
    const int lane = threadIdx.x & 63;
    int gw = (blockIdx.x * blockDim.x + threadIdx.x) >> 6;
    const int nw = (gridDim.x * blockDim.x) >> 6;
    const float bl = bias[lane];
    const char* hbl = (const char*)Hb + lane * 2;
    const int npairs = (N + 1) >> 1;

    auto phase2 = [&](int nj, int soff, float wl) -> float {
        const int wbits = __float_as_int(wl);
        float a0 = 0.f, a1 = 0.f, a2 = 0.f, a3 = 0.f;
        int q = 0;
        for (; q + 4 <= nj; q += 4) {
            const int o0 = __builtin_amdgcn_readlane(soff, q);
            const int o1 = __builtin_amdgcn_readlane(soff, q + 1);
            const int o2 = __builtin_amdgcn_readlane(soff, q + 2);
            const int o3 = __builtin_amdgcn_readlane(soff, q + 3);
            const float w0 = __int_as_float(__builtin_amdgcn_readlane(wbits, q));
            const float w1 = __int_as_float(__builtin_amdgcn_readlane(wbits, q + 1));
            const float w2 = __int_as_float(__builtin_amdgcn_readlane(wbits, q + 2));
            const float w3 = __int_as_float(__builtin_amdgcn_readlane(wbits, q + 3));
            const unsigned short h0 = *(const unsigned short*)(hbl + o0);
            const unsigned short h1 = *(const unsigned short*)(hbl + o1);
            const unsigned short h2 = *(const unsigned short*)(hbl + o2);
            const unsigned short h3 = *(const unsigned short*)(hbl + o3);
            a0 += w0 * bf2f(h0);
            a1 += w1 * bf2f(h1);
            a2 += w2 * bf2f(h2);
            a3 += w3 * bf2f(h3);
        }
        for (; q < nj; q++) {
            const int o0 = __builtin_amdgcn_readlane(soff, q);
            const float w0 = __int_as_float(__builtin_amdgcn_readlane(wbits, q));
            const unsigned short h0 = *(const unsigned short*)(hbl + o0);
            a0 += w0 * bf2f(h0);
        }
        return (a0 + a1) + (a2 + a3);
    };

    for (int p = gw; p < npairs; p += nw) {
        const int i0 = 2 * p;
        const int i1 = 2 * p + 1;
        const bool has1 = (i1 < N);

        const float scd0 = sc_d[i0];
        float es0 = sc_s[i0] + scd0;
        es0 = es0 > 0.f ? es0 : 0.2f * es0;
        float m0 = es0, denom0 = 1.f;
        float acc0 = bf2f(Hb[(size_t)i0 * 64 + lane]);
        int j0 = rowptr[i0];
        const int je0 = rowptr[i0 + 1];

        float scd1 = 0.f, m1 = 0.f, denom1 = 1.f, acc1 = 0.f;
        int j1 = 0, je1 = 0;
        if (has1) {
            scd1 = sc_d[i1];
            float es1 = sc_s[i1] + scd1;
            es1 = es1 > 0.f ? es1 : 0.2f * es1;
            m1 = es1;
            acc1 = bf2f(Hb[(size_t)i1 * 64 + lane]);
            j1 = rowptr[i1];
            je1 = rowptr[i1 + 1];
        }

        while (j0 < je0 || j1 < je1) {
            int nj0 = 0, nj1 = 0;
            int soff0 = 0, soff1 = 0;
            float el0 = -1e30f, el1 = -1e30f;
            if (j0 < je0) {
                nj0 = min(64, je0 - j0);
                if (lane < nj0) {
                    const int sl = col[j0 + lane];
                    soff0 = sl << 7;
                    const float ev = sc_s[sl] + scd0;
                    el0 = ev > 0.f ? ev : 0.2f * ev;
                }
            }
            if (j1 < je1) {
                nj1 = min(64, je1 - j1);
                if (lane < nj1) {
                    const int sl = col[j1 + lane];
                    soff1 = sl << 7;
                    const float ev = sc_s[sl] + scd1;
                    el1 = ev > 0.f ? ev : 0.2f * ev;
                }
            }
            if (nj0) {
                float cm = el0;
#pragma unroll
                for (int off = 32; off; off >>= 1) cm = fmaxf(cm, __shfl_xor(cm, off));
                const float mn = fmaxf(m0, cm);
                float wl = (lane < nj0) ? __expf(el0 - mn) : 0.f;
                float wsum = wl;
#pragma unroll
                for (int off = 32; off; off >>= 1) wsum += __shfl_xor(wsum, off);
                const float scale = __expf(m0 - mn);
                denom0 = denom0 * scale + wsum;
                acc0 = acc0 * scale + phase2(nj0, soff0, wl);
                m0 = mn;
                j0 += 64;
            }
            if (nj1) {
                float cm = el1;
#pragma unroll
                for (int off = 32; off; off >>= 1) cm = fmaxf(cm, __shfl_xor(cm, off));
                const float mn = fmaxf(m1, cm);
                float wl = (lane < nj1) ? __expf(el1 - mn) : 0.f;
                float wsum = wl;
#pragma unroll
                for (int off = 32; off; off >>= 1) wsum += __shfl_xor(wsum, off);
                const float scale = __expf(m1 - mn);
                denom1 = denom1 * scale + wsum;
                acc1 = acc1 * scale + phase2(nj1, soff1, wl);
                m1 = mn;
                j1 += 64;
            }
        }

        {
            float o = acc0 / denom0 + bl;
            if (RELU) o = o > 0.f ? o : 0.f;
            if (OUTBF) ((unsigned short*)Out)[(size_t)i0 * 64 + lane] = f2bf(o);
            else       ((float*)Out)[(size_t)i0 * 64 + lane] = o;
        }
        if (has1) {
            float o = acc1 / denom1 + bl;
            if (RELU) o = o > 0.f ? o : 0.f;
            if (OUTBF) ((unsigned short*)Out)[(size_t)i1 * 64 + lane] = f2bf(o);
            else       ((float*)Out)[(size_t)i1 * 64 + lane] = o;
        }
    }
}

// ---------------- pooling (batch sorted; small chunks, many waves) ----------------

__global__ void pool_kernel(const float* __restrict__ H, const int* __restrict__ batch,
                            float* __restrict__ sums, int* __restrict__ cnts, int N) {
    const int CHUNK = 32;
    const int lane = threadIdx.x & 63;
    int gw = (blockIdx.x * blockDim.x + threadIdx.x) >> 6;
    const int nw = (gridDim.x * blockDim.x) >> 6;
    const int nchunks = (N + CHUNK - 1) / CHUNK;
    for (int c = gw; c < nchunks; c += nw) {
        const int lo = c * CHUNK;
        const int hi = min(lo + CHUNK, N);
        int curb = batch[lo];
        float acc = 0.f;
        int cnt = 0;
        for (int n = lo; n < hi; n++) {
            int b = batch[n];
            if (b != curb) {
                unsafeAtomicAdd(&sums[(size_t)curb * 64 + lane], acc);
                if (lane == 0) atomicAdd(&cnts[curb], cnt);
                acc = 0.f; cnt = 0; curb = b;
            }
            acc += H[(size_t)n * 64 + lane];
            cnt++;
        }
        unsafeAtomicAdd(&sums[(size_t)curb * 64 + lane], acc);
        if (lane == 0) atomicAdd(&cnts[curb], cnt);
    }
}

// ---------------- final MLP + log_softmax ----------------
__global__ void mlp_kernel(const float* __restrict__ sums, const int* __restrict__ cnts,
                           const float* __restrict__ lw, const float* __restrict__ lb,
                           const float* __restrict__ cw, const float* __restrict__ cb,
                           float* __restrict__ out) {
    __shared__ float gv[64];
    __shared__ float z[32];
    __shared__ float logits[6];
    const int g = blockIdx.x;
    const int t = threadIdx.x;

    float cnt = (float)cnts[g];
    cnt = cnt > 1.f ? cnt : 1.f;
    gv[t] = sums[(size_t)g * 64 + t] / cnt;
    __syncthreads();

    if (t < 32) {
        float acc = lb[t];
#pragma unroll
        for (int k = 0; k < 64; k++) acc += gv[k] * lw[k * 32 + t];
        z[t] = acc > 0.f ? acc : 0.f;
    }
    __syncthreads();
    if (t < 6) {
        float acc = cb[t];
#pragma unroll
        for (int k = 0; k < 32; k++) acc += z[k] * cw[k * 6 + t];
        logits[t] = acc;
    }
    __syncthreads();
    if (t == 0) {
        float m = logits[0];
#pragma unroll
        for (int i = 1; i < 6; i++) m = fmaxf(m, logits[i]);
        float s = 0.f;
#pragma unroll
        for (int i = 0; i < 6; i++) s += expf(logits[i] - m);
        float lse = m + logf(s);
#pragma unroll
        for (int i = 0; i < 6; i++) out[(size_t)g * 6 + i] = logits[i] - lse;
    }
}

// ---------------- launch ----------------

extern "C" void kernel_launch(void* const* d_in, const int* in_sizes, int n_in,
                              void* d_out, int out_size, void* d_ws, size_t ws_size,
                              hipStream_t stream) {
    const float* x    = (const float*)d_in[0];
    const int*   ei   = (const int*)d_in[1];
    const int*   batch= (const int*)d_in[2];
    const float* W1   = (const float*)d_in[3];
    const float* as1  = (const float*)d_in[4];
    const float* ad1  = (const float*)d_in[5];
    const float* b1   = (const float*)d_in[6];
    const float* W2   = (const float*)d_in[7];
    const float* as2  = (const float*)d_in[8];
    const float* ad2  = (const float*)d_in[9];
    const float* b2   = (const float*)d_in[10];
    const float* lw   = (const float*)d_in[11];
    const float* lb   = (const float*)d_in[12];
    const float* cw   = (const float*)d_in[13];
    const float* cb   = (const float*)d_in[14];
    float* out = (float*)d_out;

    const int N  = in_sizes[0] / 128;
    const int E  = in_sizes[1] / 2;
    const int G  = out_size / 6;
    const int NB = (N + BSZ - 1) / BSZ;

    char* ws = (char*)d_ws;
    size_t off = 0;
    auto alloc = [&](size_t bytes) {
        void* p = ws + off;
        off += (bytes + 255) & ~size_t(255);
        return p;
    };
    float*          hB     = (float*)alloc((size_t)N * 64 * 4);
    unsigned short* hB1b   = (unsigned short*)alloc((size_t)N * 64 * 2);
    unsigned short* Hb     = (unsigned short*)alloc((size_t)N * 64 * 2);
    float*          sc_s   = (float*)alloc((size_t)N * 4);
    float*          sc_d   = (float*)alloc((size_t)N * 4);
    int*            rowptr = (int*)alloc((size_t)(N + 1) * 4);
    int*            colidx = (int*)alloc((size_t)E * 4);
    unsigned*       staged = (unsigned*)alloc((size_t)NB * BCAP * 4);
    int*            bbase  = (int*)alloc((size_t)257 * 4);
    int*            bcur   = (int*)alloc((size_t)256 * 4);
    float*          psum   = (float*)alloc((size_t)G * 64 * 4);
    int*            pcnt   = (int*)alloc((size_t)G * 4);
    (void)ws_size;

    const int TB = 256;
    const int gemm_grid = (N + 63) / 64;
    const int part_blocks = (E + CH - 1) / CH;

    // ---- CSR build by dst (no pre-histogram) ----
    bucket_init_kernel<<<1, 256, 0, stream>>>(bcur, NB);
    partition_kernel<<<part_blocks, 256, 0, stream>>>(ei, E, bcur, staged);
    bucket_scan_kernel<<<1, 256, 0, stream>>>(bcur, bbase, NB, E);
    place_kernel<<<NB, 256, 0, stream>>>(staged, bcur, bbase, rowptr, colidx, N, E, NB);

    // ---- layer 1 ----
    gat_gemm_mfma<128, false><<<gemm_grid, TB, 0, stream>>>(x, W1, as1, ad1, Hb, sc_s, sc_d, N);
    gat_fused_agg<true, true><<<2048, TB, 0, stream>>>(rowptr, colidx, sc_s, sc_d, Hb, b1, hB1b, N);

    // ---- layer 2 ----
    gat_gemm_mfma<64, true><<<gemm_grid, TB, 0, stream>>>(hB1b, W2, as2, ad2, Hb, sc_s, sc_d, N);
    gat_fused_agg<false, false><<<2048, TB, 0, stream>>>(rowptr, colidx, sc_s, sc_d, Hb, b2, hB, N);

    // ---- pooling + MLP head ----
    hipMemsetAsync(psum, 0, (size_t)G * 64 * 4, stream);
    hipMemsetAsync(pcnt, 0, (size_t)G * 4, stream);
    pool_kernel<<<1024, TB, 0, stream>>>(hB, batch, psum, pcnt, N);
    mlp_kernel<<<G, 64, 0, stream>>>(psum, pcnt, lw, lb, cw, cb, out);
}